// Round 5
// baseline (74.391 us; speedup 1.0000x reference)
//
#include <hip/hip_runtime.h>
#include <hip/hip_fp16.h>
#include <cstdint>
#include <cmath>

#define HIDDEN   768
#define NPAIR    384               // (sin,cos) pairs per row
#define SEQ_N    4096
#define LN_EPS   1e-12f
#define R_HI     20                // p>>8        in [0,20)
#define R_MID    16                // (p>>4)&15
#define R_LO     16                // p&15
#define R_TOT    (R_HI + R_MID + R_LO)          // 52 rows
#define TBL_U4   (R_TOT * NPAIR * 4 / 16)       // 4992 uint4 = 79872 B
#define NBLK     512               // persistent blocks: 2 per CU
#define NTHR     512               // 8 waves per block

typedef float    f4v __attribute__((ext_vector_type(4)));
typedef _Float16 h4v __attribute__((ext_vector_type(4)));

// ---------------------------------------------------------------------------
// Kernel 1: build the 3-level f16 angle table in d_ws.
//   row r < 20:        angle = (r<<8) * d_i      (hi)
//   row 20 <= r < 36:  angle = ((r-20)<<4) * d_i (mid)
//   row 36 <= r < 52:  angle = (r-36) * d_i      (lo)
// d_i = exp(-2i * ln(10000)/HIDDEN).  pe[p] = rotation(hi) ∘ rotation(mid) ∘
// rotation(lo) applied via two chained angle-additions (exact up to f16
// quantization of the factors, ~7e-4 absolute).
// ---------------------------------------------------------------------------
__global__ __launch_bounds__(256) void pe_tables3_kernel(__half2* __restrict__ T) {
    const int total = R_TOT * NPAIR;
    int idx = blockIdx.x * 256 + threadIdx.x;
    if (idx >= total) return;
    int r = idx / NPAIR;
    int i = idx % NPAIR;
    const float L = logf(10000.0f) / (float)HIDDEN;
    float div = expf(-2.0f * (float)i * L);
    int p;
    if (r < R_HI)              p = r << 8;
    else if (r < R_HI + R_MID) p = (r - R_HI) << 4;
    else                       p = r - R_HI - R_MID;
    float s, c;
    sincosf((float)p * div, &s, &c);
    T[idx] = __floats2half2_rn(s, c);     // x = sin, y = cos
}

// Chained rotation: (sin,cos)(H+M+L) accumulated into x (2 pairs per call).
// h/m/l = (s0,c0,s1,c1) for pair0/pair1 of the hi/mid/lo rows.
__device__ __forceinline__ void pe_add3(float4& x, const h4v h, const h4v m, const h4v l) {
    const float sh0 = (float)h.x, ch0 = (float)h.y, sh1 = (float)h.z, ch1 = (float)h.w;
    const float sm0 = (float)m.x, cm0 = (float)m.y, sm1 = (float)m.z, cm1 = (float)m.w;
    const float sl0 = (float)l.x, cl0 = (float)l.y, sl1 = (float)l.z, cl1 = (float)l.w;
    const float sml0 = fmaf(sm0, cl0, cm0 * sl0);
    const float cml0 = fmaf(cm0, cl0, -(sm0 * sl0));
    x.x = fmaf(sh0, cml0, fmaf(ch0, sml0, x.x));          // += sin(H+M+L)
    x.y = fmaf(ch0, cml0, fmaf(-sh0, sml0, x.y));         // += cos(H+M+L)
    const float sml1 = fmaf(sm1, cl1, cm1 * sl1);
    const float cml1 = fmaf(cm1, cl1, -(sm1 * sl1));
    x.z = fmaf(sh1, cml1, fmaf(ch1, sml1, x.z));
    x.w = fmaf(ch1, cml1, fmaf(-sh1, sml1, x.w));
}

__device__ __forceinline__ h4v ldsT(const __half2* __restrict__ T, int rowbase, int i0) {
    return *reinterpret_cast<const h4v*>(T + rowbase + i0);   // 8B aligned (i0 even)
}

// ---------------------------------------------------------------------------
// Kernel 2: persistent-block fused embedding-sum + LayerNorm.
// 512 threads (8 waves), 2 blocks/CU; 80 KB LDS trig table staged once per
// block; each wave grid-strides over tokens (1 token at a time, indices
// prefetched one token ahead so word-row gathers hide under LDS trig).
// ---------------------------------------------------------------------------
__global__ __launch_bounds__(NTHR, 4) void emb_ln_kernel(
    const int*   __restrict__ ids,       // (B*N)
    const int*   __restrict__ svec,      // (B*N, 3)
    const int*   __restrict__ tt,        // (B*N)
    const float* __restrict__ word_emb,  // (VOCAB, HIDDEN)
    const float* __restrict__ type_emb,  // (2, HIDDEN)
    const float* __restrict__ gamma,     // (HIDDEN)
    const float* __restrict__ beta,      // (HIDDEN)
    const uint4* __restrict__ Tg,        // staged f16 table, TBL_U4 uint4
    float*       __restrict__ out,       // (B*N, HIDDEN)
    int n_tokens)
{
    __shared__ uint4 smem[TBL_U4];       // 79872 B
    const int tid = threadIdx.x;
    for (int i = tid; i < TBL_U4; i += NTHR) smem[i] = Tg[i];
    __syncthreads();

    const int lane   = tid & 63;
    const int gw     = blockIdx.x * (NTHR / 64) + (tid >> 6);
    const int stride = gridDim.x * (NTHR / 64);
    const __half2* T = reinterpret_cast<const __half2*>(smem);

    // ---- per-wave register caches: gamma, beta, both type rows ----
    const float4* g4 = reinterpret_cast<const float4*>(gamma);
    const float4* b4 = reinterpret_cast<const float4*>(beta);
    const float4* t4 = reinterpret_cast<const float4*>(type_emb);
    float4 gc[3], bc[3], tA[3], tB[3];
    #pragma unroll
    for (int k = 0; k < 3; ++k) {
        const int d4 = lane + 64 * k;
        gc[k] = g4[d4]; bc[k] = b4[d4];
        tA[k] = t4[d4]; tB[k] = t4[(HIDDEN / 4) + d4];
    }

    int tok = gw;
    if (tok >= n_tokens) return;

    // prefetched indices for the current token
    int id = ids[tok], ty = tt[tok];
    int p0 = svec[3 * tok], p1 = svec[3 * tok + 1], p2 = svec[3 * tok + 2];

    while (tok < n_tokens) {
        const int n = tok & (SEQ_N - 1);

        // issue word-row gathers first; they drain under the LDS trig phase
        const float4* wrow = reinterpret_cast<const float4*>(word_emb + (size_t)id * HIDDEN);
        float4 w0 = wrow[lane], w1 = wrow[lane + 64], w2 = wrow[lane + 128];

        // prefetch next token's indices (wave-uniform scalar loads)
        const int tnext = tok + stride;
        int id_n = 0, ty_n = 0, q0 = 0, q1 = 0, q2 = 0;
        if (tnext < n_tokens) {
            id_n = ids[tnext]; ty_n = tt[tnext];
            q0 = svec[3 * tnext]; q1 = svec[3 * tnext + 1]; q2 = svec[3 * tnext + 2];
        }

        // wave-uniform LDS row bases for 4 positions x 3 levels
        const int r0h = (n  >> 8) * NPAIR, r0m = (R_HI + ((n  >> 4) & 15)) * NPAIR, r0l = (R_HI + R_MID + (n  & 15)) * NPAIR;
        const int r1h = (p0 >> 8) * NPAIR, r1m = (R_HI + ((p0 >> 4) & 15)) * NPAIR, r1l = (R_HI + R_MID + (p0 & 15)) * NPAIR;
        const int r2h = (p1 >> 8) * NPAIR, r2m = (R_HI + ((p1 >> 4) & 15)) * NPAIR, r2l = (R_HI + R_MID + (p1 & 15)) * NPAIR;
        const int r3h = (p2 >> 8) * NPAIR, r3m = (R_HI + ((p2 >> 4) & 15)) * NPAIR, r3l = (R_HI + R_MID + (p2 & 15)) * NPAIR;

        // x starts from the register-cached type row; PE accumulates on top
        float4 x[3];
        #pragma unroll
        for (int k = 0; k < 3; ++k) x[k] = ty ? tB[k] : tA[k];

        #pragma unroll
        for (int k = 0; k < 3; ++k) {
            const int i0 = 2 * (lane + 64 * k);
            pe_add3(x[k], ldsT(T, r0h, i0), ldsT(T, r0m, i0), ldsT(T, r0l, i0));
            pe_add3(x[k], ldsT(T, r1h, i0), ldsT(T, r1m, i0), ldsT(T, r1l, i0));
            pe_add3(x[k], ldsT(T, r2h, i0), ldsT(T, r2m, i0), ldsT(T, r2l, i0));
            pe_add3(x[k], ldsT(T, r3h, i0), ldsT(T, r3m, i0), ldsT(T, r3l, i0));
        }

        // fold in the word row (loads have had the whole trig phase to land)
        x[0].x += w0.x; x[0].y += w0.y; x[0].z += w0.z; x[0].w += w0.w;
        x[1].x += w1.x; x[1].y += w1.y; x[1].z += w1.z; x[1].w += w1.w;
        x[2].x += w2.x; x[2].y += w2.y; x[2].z += w2.z; x[2].w += w2.w;

        float s = 0.0f, ss = 0.0f;
        #pragma unroll
        for (int k = 0; k < 3; ++k) {
            s  += x[k].x + x[k].y + x[k].z + x[k].w;
            ss += x[k].x * x[k].x + x[k].y * x[k].y + x[k].z * x[k].z + x[k].w * x[k].w;
        }
        #pragma unroll
        for (int off = 1; off < 64; off <<= 1) {
            s  += __shfl_xor(s,  off);
            ss += __shfl_xor(ss, off);
        }

        const float mean = s * (1.0f / (float)HIDDEN);
        const float var  = ss * (1.0f / (float)HIDDEN) - mean * mean;
        const float inv  = rsqrtf(var + LN_EPS);

        f4v* orow = reinterpret_cast<f4v*>(out + (size_t)tok * HIDDEN);
        #pragma unroll
        for (int k = 0; k < 3; ++k) {
            const int d4 = lane + 64 * k;
            f4v r;
            r.x = (x[k].x - mean) * inv * gc[k].x + bc[k].x;
            r.y = (x[k].y - mean) * inv * gc[k].y + bc[k].y;
            r.z = (x[k].z - mean) * inv * gc[k].z + bc[k].z;
            r.w = (x[k].w - mean) * inv * gc[k].w + bc[k].w;
            __builtin_nontemporal_store(r, &orow[d4]);
        }

        tok = tnext; id = id_n; ty = ty_n; p0 = q0; p1 = q1; p2 = q2;
    }
}

extern "C" void kernel_launch(void* const* d_in, const int* in_sizes, int n_in,
                              void* d_out, int out_size, void* d_ws, size_t ws_size,
                              hipStream_t stream) {
    const int*   ids      = (const int*)d_in[0];   // input_ids      (B*N)
    const int*   svec     = (const int*)d_in[1];   // tok_struct_vec (B*N*3)
    const int*   tt       = (const int*)d_in[2];   // token_type_ids (B*N)
    const float* word_emb = (const float*)d_in[3]; // (VOCAB, HIDDEN)
    const float* type_emb = (const float*)d_in[4]; // (2, HIDDEN)
    const float* gamma    = (const float*)d_in[5]; // (HIDDEN)
    const float* beta     = (const float*)d_in[6]; // (HIDDEN)
    float*       out      = (float*)d_out;

    const int n_tokens = in_sizes[0];

    __half2* T = (__half2*)d_ws;                   // 52*384 half2 = 80 KB
    const int total_tab = R_TOT * NPAIR;
    pe_tables3_kernel<<<(total_tab + 255) / 256, 256, 0, stream>>>(T);
    emb_ln_kernel<<<NBLK, NTHR, 0, stream>>>(
        ids, svec, tt, word_emb, type_emb, gamma, beta,
        (const uint4*)d_ws, out, n_tokens);
}

// Round 6
// 53.247 us; speedup vs baseline: 1.3971x; 1.3971x over previous
//
#include <hip/hip_runtime.h>
#include <hip/hip_fp16.h>
#include <cstdint>
#include <cmath>

#define HIDDEN   768
#define NPAIR    (HIDDEN / 2)      // 384 (sin,cos) pairs per row
#define SEQ_N    4096
#define LN_EPS   1e-12f
#define N_HI     80                // angle = 64*hi*d_i, hi in [0,80)
#define N_LO     64                // angle = lo*d_i,    lo in [0,64)

typedef float    f4v __attribute__((ext_vector_type(4)));
typedef _Float16 h4v __attribute__((ext_vector_type(4)));

// ---------------------------------------------------------------------------
// Kernel 1: build the two compact angle-addition tables in d_ws as f16 pairs.
//   T[hi][i]        = (sin, cos)(64*hi * d_i)   hi in [0,80)
//   T[80+lo][i]     = (sin, cos)(lo    * d_i)   lo in [0,64)
// d_i = exp(-2i * ln(10000)/HIDDEN).  pe[p] reconstructed via sin(A+B)/
// cos(A+B), p = 64*hi + lo, factors quantized to f16 (~5e-4 abs error).
// Tables = 221 KB -> comfortably L2-resident on every XCD.
// ---------------------------------------------------------------------------
__global__ __launch_bounds__(256) void pe_tables_kernel(__half2* __restrict__ T) {
    const int total = (N_HI + N_LO) * NPAIR;
    int idx = blockIdx.x * 256 + threadIdx.x;
    if (idx >= total) return;
    int r = idx / NPAIR;
    int i = idx % NPAIR;
    const float L = logf(10000.0f) / (float)HIDDEN;
    float div = expf(-2.0f * (float)i * L);
    int p = (r < N_HI) ? (r << 6) : (r - N_HI);
    float s, c;
    sincosf((float)p * div, &s, &c);
    T[idx] = __floats2half2_rn(s, c);     // x = sin, y = cos
}

// sin(A+B) = sA*cB + cA*sB ; cos(A+B) = cA*cB - sA*sB
// a = (sinA0, cosA0, sinA1, cosA1), b = (sinB0, cosB0, sinB1, cosB1)  [f16]
__device__ __forceinline__ void pe_acc(float4& x, const h4v a, const h4v b) {
    const float sA0 = (float)a.x, cA0 = (float)a.y, sA1 = (float)a.z, cA1 = (float)a.w;
    const float sB0 = (float)b.x, cB0 = (float)b.y, sB1 = (float)b.z, cB1 = (float)b.w;
    x.x = fmaf(sA0, cB0, fmaf(cA0, sB0, x.x));
    x.y = fmaf(cA0, cB0, fmaf(-sA0, sB0, x.y));
    x.z = fmaf(sA1, cB1, fmaf(cA1, sB1, x.z));
    x.w = fmaf(cA1, cB1, fmaf(-sA1, sB1, x.w));
}

// ---------------------------------------------------------------------------
// Kernel 2: fused embedding-sum + LayerNorm (R2 structure: one 64-lane wave
// per token, 4 waves per 256-thread block).  Table rows are f16 pairs, so
// each row read is an 8B/lane coalesced load — half the L2 bytes of f32.
// ---------------------------------------------------------------------------
__global__ __launch_bounds__(256) void emb_ln_kernel(
    const int*     __restrict__ ids,       // (B*N)
    const int*     __restrict__ svec,      // (B*N, 3)
    const int*     __restrict__ tt,        // (B*N)
    const float*   __restrict__ word_emb,  // (VOCAB, HIDDEN)
    const float*   __restrict__ type_emb,  // (2, HIDDEN)
    const float*   __restrict__ gamma,     // (HIDDEN)
    const float*   __restrict__ beta,      // (HIDDEN)
    const __half2* __restrict__ T,         // (N_HI+N_LO, NPAIR) f16 (sin,cos)
    float*         __restrict__ out,       // (B*N, HIDDEN)
    int n_tokens)
{
    const int wave = threadIdx.x >> 6;
    const int lane = threadIdx.x & 63;
    const int tok  = blockIdx.x * 4 + wave;
    if (tok >= n_tokens) return;

    const int n  = tok & (SEQ_N - 1);     // position within sequence
    const int id = ids[tok];
    const int ty = tt[tok];
    const int p0 = svec[tok * 3 + 0];
    const int p1 = svec[tok * 3 + 1];
    const int p2 = svec[tok * 3 + 2];

    const float4* wrow = reinterpret_cast<const float4*>(word_emb + (size_t)id * HIDDEN);
    const float4* trow = reinterpret_cast<const float4*>(type_emb + (size_t)ty * HIDDEN);

    // Table row pointers (h4v = 2 (sin,cos) pairs = 8B per lane).
    #define T1ROW(p) reinterpret_cast<const h4v*>(T + (size_t)((p) >> 6) * NPAIR)
    #define T2ROW(p) reinterpret_cast<const h4v*>(T + (size_t)(N_HI + ((p) & 63)) * NPAIR)
    const h4v* A0 = T1ROW(n),  *B0 = T2ROW(n);
    const h4v* A1 = T1ROW(p0), *B1 = T2ROW(p0);
    const h4v* A2 = T1ROW(p1), *B2 = T2ROW(p1);
    const h4v* A3 = T1ROW(p2), *B3 = T2ROW(p2);
    #undef T1ROW
    #undef T2ROW

    float4 acc[3];
    float s = 0.0f, ss = 0.0f;

    #pragma unroll
    for (int k = 0; k < 3; ++k) {
        const int d4 = lane + 64 * k;   // float4-chunk index == h4v pair-pair index

        // ---- issue all 10 independent gathers for this round ----
        float4 w = wrow[d4];
        float4 t = trow[d4];
        h4v a0 = A0[d4], b0 = B0[d4];
        h4v a1 = A1[d4], b1 = B1[d4];
        h4v a2 = A2[d4], b2 = B2[d4];
        h4v a3 = A3[d4], b3 = B3[d4];

        float4 x;
        x.x = w.x + t.x; x.y = w.y + t.y; x.z = w.z + t.z; x.w = w.w + t.w;
        pe_acc(x, a0, b0);
        pe_acc(x, a1, b1);
        pe_acc(x, a2, b2);
        pe_acc(x, a3, b3);

        acc[k] = x;
        s  += x.x + x.y + x.z + x.w;
        ss += x.x * x.x + x.y * x.y + x.z * x.z + x.w * x.w;
    }

    // 64-lane butterfly reduction: every lane ends with the full sums.
    #pragma unroll
    for (int off = 1; off < 64; off <<= 1) {
        s  += __shfl_xor(s,  off);
        ss += __shfl_xor(ss, off);
    }

    const float mean = s * (1.0f / (float)HIDDEN);
    const float var  = ss * (1.0f / (float)HIDDEN) - mean * mean;
    const float inv  = rsqrtf(var + LN_EPS);

    const float4* g4 = reinterpret_cast<const float4*>(gamma);
    const float4* b4 = reinterpret_cast<const float4*>(beta);
    float4* orow = reinterpret_cast<float4*>(out + (size_t)tok * HIDDEN);

    #pragma unroll
    for (int k = 0; k < 3; ++k) {
        const int d4 = lane + 64 * k;
        const float4 g = g4[d4];
        const float4 b = b4[d4];
        const float4 x = acc[k];
        float4 r;
        r.x = (x.x - mean) * inv * g.x + b.x;
        r.y = (x.y - mean) * inv * g.y + b.y;
        r.z = (x.z - mean) * inv * g.z + b.z;
        r.w = (x.w - mean) * inv * g.w + b.w;
        orow[d4] = r;
    }
}

extern "C" void kernel_launch(void* const* d_in, const int* in_sizes, int n_in,
                              void* d_out, int out_size, void* d_ws, size_t ws_size,
                              hipStream_t stream) {
    const int*   ids      = (const int*)d_in[0];   // input_ids      (B*N)
    const int*   svec     = (const int*)d_in[1];   // tok_struct_vec (B*N*3)
    const int*   tt       = (const int*)d_in[2];   // token_type_ids (B*N)
    const float* word_emb = (const float*)d_in[3]; // (VOCAB, HIDDEN)
    const float* type_emb = (const float*)d_in[4]; // (2, HIDDEN)
    const float* gamma    = (const float*)d_in[5]; // (HIDDEN)
    const float* beta     = (const float*)d_in[6]; // (HIDDEN)
    float*       out      = (float*)d_out;

    const int n_tokens = in_sizes[0];
    const int grid_main = (n_tokens + 3) / 4;      // 4 waves (tokens) per block

    // Workspace: 144 rows x 384 __half2 = 221 KB.
    __half2* T = (__half2*)d_ws;
    const int total_tab = (N_HI + N_LO) * NPAIR;
    pe_tables_kernel<<<(total_tab + 255) / 256, 256, 0, stream>>>(T);
    emb_ln_kernel<<<grid_main, 256, 0, stream>>>(
        ids, svec, tt, word_emb, type_emb, gamma, beta, T, out, n_tokens);
}